// Round 1
// baseline (4628.865 us; speedup 1.0000x reference)
//
#include <hip/hip_runtime.h>
#include <stdint.h>

// B=32, L=256, D=128. Reader LSTM scan + attention-memory writer scan. FP32.
// Inputs: x(32,256,128), Wr(128,512), Ur(128,512), br(512),
//         Ww(128,512), Uw(128,512), bw(512), Wc(256,128), bc(128)
// Output: final writer h (32,128) fp32.
//
// v2 structure (split + precompute):
//   wtrans x5     : transpose weights to float4 k-tiles (as before)
//   xw_gemm       : XW[b,t,:] = x[b,t,:]@Wr + br   (parallel, whole chip)
//   reader_kernel : sequential scan, Ur held in registers (32xfloat4/thread),
//                   per step: 1 global load (XW) + LDS h-dot (4 accumulators)
//   owc_gemm      : OWc[b,t,:] = og[b,t,:]@Wc_top + bc (parallel)
//   writer_kernel : as before, minus o@Wc_top (precomputed), Wc_bot tiles
//                   held in registers, 4-accumulator z-matmul.
// Workspace: 6,586,368 floats = 26.35 MB.

#define LL 256

typedef float v2f __attribute__((ext_vector_type(2)));

__device__ __forceinline__ float hsig(float x) { return fminf(fmaxf(fmaf(x, 0.2f, 0.5f), 0.f), 1.f); }
__device__ __forceinline__ float tanh_fast(float x) {
  x = fminf(fmaxf(x, -15.f), 15.f);
  float e = __expf(2.f * x);
  return (e - 1.f) / (e + 1.f);
}

// ---- Prep: transpose fp32 W[K][J] (row-major) -> float4 k-tiles ----------
// dst float4 index (k>>2)*J + j holds rows k..k+3 of column j.
__global__ __launch_bounds__(512) void wtrans_kernel(const float* __restrict__ src,
                                                     float* __restrict__ dst, int jshift) {
  int idx = blockIdx.x * 512 + threadIdx.x;
  int J = 1 << jshift;
  int k = idx >> jshift, j = idx & (J - 1);
  dst[(((size_t)(k >> 2) << jshift) + j) * 4 + (k & 3)] = src[idx];
}

// ---- XW = x @ Wr + br, all (b,t) rows in parallel -------------------------
// grid 1024 = 32 b x 32 tgroups (8 t each), 512 threads (one output col each).
__global__ __launch_bounds__(512) void xw_gemm(const float* __restrict__ x,
                                               const float4* __restrict__ WrT4,
                                               const float* __restrict__ br,
                                               float* __restrict__ XW) {
  alignas(16) __shared__ float xs[8][128];
  const int b = blockIdx.x >> 5, tg = blockIdx.x & 31, tid = threadIdx.x;
  const float* xg = x + ((size_t)b * LL + tg * 8) * 128;
  if (tid < 256) ((float4*)&xs[0][0])[tid] = ((const float4*)xg)[tid];
  __syncthreads();
  float acc[8];
#pragma unroll
  for (int r = 0; r < 8; r++) acc[r] = 0.f;
#pragma unroll 8
  for (int i4 = 0; i4 < 32; i4++) {
    float4 w4 = WrT4[i4 * 512 + tid];
#pragma unroll
    for (int r = 0; r < 8; r++) {
      float4 v = *(const float4*)&xs[r][4 * i4];
      acc[r] += w4.x * v.x + w4.y * v.y + w4.z * v.z + w4.w * v.w;
    }
  }
  const float brj = br[tid];
  float* o = XW + ((size_t)b * LL + tg * 8) * 512;
#pragma unroll
  for (int r = 0; r < 8; r++) o[r * 512 + tid] = acc[r] + brj;
}

// ---- OWc = og @ Wc_top + bc, all (b,t) rows in parallel -------------------
// grid 1024 = 32 b x 32 tgroups (8 t each), 512 threads = (j in 0..127, r2 in 0..3).
__global__ __launch_bounds__(512) void owc_gemm(const float* __restrict__ og,
                                                const float4* __restrict__ WcT4,
                                                const float* __restrict__ bc,
                                                float* __restrict__ OWc) {
  alignas(16) __shared__ float os[8][128];
  const int b = blockIdx.x >> 5, tg = blockIdx.x & 31, tid = threadIdx.x;
  const int j = tid & 127, r2 = tid >> 7;  // rows r2*2, r2*2+1
  const float* g = og + ((size_t)b * LL + tg * 8) * 128;
  if (tid < 256) ((float4*)&os[0][0])[tid] = ((const float4*)g)[tid];
  __syncthreads();
  float a0 = 0.f, a1 = 0.f;
#pragma unroll 8
  for (int i4 = 0; i4 < 32; i4++) {  // top half of Wc: tiles 0..31
    float4 w4 = WcT4[i4 * 128 + j];
    float4 v0 = *(const float4*)&os[r2 * 2][4 * i4];
    float4 v1 = *(const float4*)&os[r2 * 2 + 1][4 * i4];
    a0 += w4.x * v0.x + w4.y * v0.y + w4.z * v0.z + w4.w * v0.w;
    a1 += w4.x * v1.x + w4.y * v1.y + w4.z * v1.z + w4.w * v1.w;
  }
  const float bcj = bc[j];
  float* o = OWc + ((size_t)b * LL + tg * 8) * 128;
  o[(r2 * 2) * 128 + j] = a0 + bcj;
  o[(r2 * 2 + 1) * 128 + j] = a1 + bcj;
}

// ---- Reader: sequential LSTM scan, Ur register-resident -------------------
__global__ __launch_bounds__(512, 2) void reader_kernel(const float4* __restrict__ UrT4,
                                                        const float* __restrict__ XW,
                                                        float* __restrict__ og) {
  alignas(16) __shared__ float h_s[128];
  alignas(16) __shared__ float pp_s[512];
  const int b = blockIdx.x, tid = threadIdx.x;
  const float* XWb = XW + (size_t)b * LL * 512;
  float* ogb = og + (size_t)b * LL * 128;

  float4 U[32];  // column tid of Ur, held for the whole scan (128 VGPRs)
#pragma unroll
  for (int i4 = 0; i4 < 32; i4++) U[i4] = UrT4[i4 * 512 + tid];

  float c_r = 0.f;
  if (tid < 128) h_s[tid] = 0.f;
  float xwv = XWb[tid];  // z-row for t=0 (x@Wr + br precomputed)
  __syncthreads();

  for (int t = 0; t < LL; t++) {
    float xw_n = (t + 1 < LL) ? XWb[(t + 1) * 512 + tid] : 0.f;  // prefetch
    v2f acc[4] = {{0.f, 0.f}, {0.f, 0.f}, {0.f, 0.f}, {0.f, 0.f}};
#pragma unroll
    for (int i4 = 0; i4 < 32; i4++) {
      float4 v = *(const float4*)&h_s[4 * i4];
      float4 w = U[i4];
      acc[i4 & 3] += (v2f){w.x, w.y} * (v2f){v.x, v.y};
      acc[i4 & 3] += (v2f){w.z, w.w} * (v2f){v.z, v.w};
    }
    v2f A = (acc[0] + acc[1]) + (acc[2] + acc[3]);
    pp_s[tid] = A.x + A.y + xwv;
    __syncthreads();
    if (tid < 128) {
      float zi = pp_s[tid], zf = pp_s[128 + tid], zg = pp_s[256 + tid], zo = pp_s[384 + tid];
      float ii = hsig(zi), ff = hsig(zf), gg = tanh_fast(zg), oo = hsig(zo);
      c_r = fmaf(ff, c_r, ii * gg);
      float h = oo * tanh_fast(c_r);
      h_s[tid] = h;
      ogb[t * 128 + tid] = h;
    }
    __syncthreads();
    xwv = xw_n;
  }
}

// ---- Writer: attention-memory scan ---------------------------------------
__global__ __launch_bounds__(512, 2) void writer_kernel(
    const float* __restrict__ x,
    const float4* __restrict__ WwT4, const float4* __restrict__ UwT4,
    const float4* __restrict__ WcT4,
    const float* __restrict__ bw,
    const float* __restrict__ og, const float* __restrict__ OWc,
    float* __restrict__ out) {
  alignas(16) __shared__ float h_s[128];
  alignas(16) __shared__ float osN[128];   // o_{t+1} (o_0 during prologue)
  alignas(16) __shared__ float ow_s[128];  // OWc row t
  alignas(16) __shared__ float sc_s[256], ee_s[256];
  alignas(16) __shared__ float mr_s[128], ct_s[128];
  alignas(16) __shared__ float pp_s[1024];
  __shared__ float rr_s[16];

  const int b = blockIdx.x, tid = threadIdx.x;
  const int lane = tid & 63, wv = tid >> 6;
  const int l = tid >> 1, hf = tid & 1;    // row-major role
  const int q = tid >> 6, dp = tid & 63;   // col-major role

  const float* xg = x + (size_t)b * (LL * 128);
  const float* ogb = og + (size_t)b * (LL * 128);
  const float* owb = OWc + (size_t)b * (LL * 128);

  // register-resident mem, two layouts (fp32 pairs)
  v2f Mr[32], Mc[32];
#pragma unroll
  for (int w = 0; w < 32; w++) Mr[w] = *(const v2f*)(xg + l * 128 + hf * 64 + 2 * w);
#pragma unroll
  for (int i = 0; i < 32; i++) Mc[i] = *(const v2f*)(xg + (q * 32 + i) * 128 + 2 * dp);

  // Wc bottom-half tiles held in registers (8 float4 = 32 VGPRs)
  const int jj = tid & 127, kq = tid >> 7;
  float4 WC[8];
#pragma unroll
  for (int i8 = 0; i8 < 8; i8++) WC[i8] = WcT4[(size_t)(32 + kq * 8 + i8) * 128 + jj];

  const float bwj = bw[tid];

  float c_w = 0.f;
  if (tid < 128) { h_s[tid] = 0.f; osN[tid] = ogb[tid]; }
  __syncthreads();
  { // prologue: sc_s[l] = mem0[l] . o_0
    v2f S = {0.f, 0.f};
#pragma unroll
    for (int w = 0; w < 32; w++) S += Mr[w] * (*(const v2f*)&osN[hf * 64 + 2 * w]);
    float s = S.x + S.y;
    s += __shfl_xor(s, 1);
    if (hf == 0) sc_s[l] = s;
  }
  __syncthreads();

  for (int t = 0; t < LL; t++) {
    // S1: load o_{t+1} + OWc row t; softmax max
    if (tid >= 128 && tid < 256) {
      if (t + 1 < LL) osN[tid - 128] = ogb[(t + 1) * 128 + (tid - 128)];
    } else if (tid >= 256 && tid < 384) {
      ow_s[tid - 256] = owb[t * 128 + (tid - 256)];
    }
    if (tid < 256) {
      float m = sc_s[tid];
#pragma unroll
      for (int off = 32; off > 0; off >>= 1) m = fmaxf(m, __shfl_xor(m, off));
      if (lane == 0) rr_s[wv] = m;
    }
    __syncthreads();
    // S2: exp + sum
    if (tid < 256) {
      float mx = fmaxf(fmaxf(rr_s[0], rr_s[1]), fmaxf(rr_s[2], rr_s[3]));
      float e = __expf(sc_s[tid] - mx);
      ee_s[tid] = e;
      float s2 = e;
#pragma unroll
      for (int off = 32; off > 0; off >>= 1) s2 += __shfl_xor(s2, off);
      if (lane == 0) rr_s[8 + wv] = s2;
    }
    __syncthreads();
    const float inv = 1.f / (rr_s[8] + rr_s[9] + rr_s[10] + rr_s[11]);
    // S3: m_rt partials (col-major, register-local)
    {
      v2f P = {0.f, 0.f};
#pragma unroll
      for (int i = 0; i < 32; i++) P += Mc[i] * ee_s[q * 32 + i];
      *(v2f*)&pp_s[q * 128 + 2 * dp] = P;
    }
    __syncthreads();
    // S4: m_rt final
    if (tid < 128) {
      float s = 0.f;
#pragma unroll
      for (int g = 0; g < 8; g++) s += pp_s[g * 128 + tid];
      mr_s[tid] = s * inv;
    }
    __syncthreads();
    // S5: c_t partials = m_rt @ Wc_bot (o@Wc_top precomputed in OWc)
    {
      v2f A = {0.f, 0.f};
#pragma unroll
      for (int i8 = 0; i8 < 8; i8++) {
        float4 w4 = WC[i8];
        float4 v4 = *(const float4*)&mr_s[kq * 32 + 4 * i8];
        A += (v2f){w4.x, w4.y} * (v2f){v4.x, v4.y};
        A += (v2f){w4.z, w4.w} * (v2f){v4.z, v4.w};
      }
      pp_s[kq * 128 + jj] = A.x + A.y;
    }
    __syncthreads();
    // S6: c_t final
    if (tid < 128)
      ct_s[tid] = ow_s[tid] + pp_s[tid] + pp_s[128 + tid] + pp_s[256 + tid] + pp_s[384 + tid];
    __syncthreads();
    // S7: z[j] = ct@Ww + h@Uw + bw (4 accumulators)
    {
      v2f acc[4] = {{0.f, 0.f}, {0.f, 0.f}, {0.f, 0.f}, {0.f, 0.f}};
#pragma unroll
      for (int i4 = 0; i4 < 32; i4++) {
        float4 w4 = WwT4[i4 * 512 + tid];
        float4 v4 = *(const float4*)&ct_s[4 * i4];
        acc[i4 & 3] += (v2f){w4.x, w4.y} * (v2f){v4.x, v4.y};
        acc[i4 & 3] += (v2f){w4.z, w4.w} * (v2f){v4.z, v4.w};
      }
#pragma unroll
      for (int i4 = 0; i4 < 32; i4++) {
        float4 w4 = UwT4[i4 * 512 + tid];
        float4 v4 = *(const float4*)&h_s[4 * i4];
        acc[i4 & 3] += (v2f){w4.x, w4.y} * (v2f){v4.x, v4.y};
        acc[i4 & 3] += (v2f){w4.z, w4.w} * (v2f){v4.z, v4.w};
      }
      v2f A = (acc[0] + acc[1]) + (acc[2] + acc[3]);
      pp_s[tid] = A.x + A.y + bwj;
    }
    __syncthreads();
    // S8: gates
    if (tid < 128) {
      float zi = pp_s[tid], zf = pp_s[128 + tid], zg = pp_s[256 + tid], zo = pp_s[384 + tid];
      float ii = hsig(zi), ff = hsig(zf), gg = tanh_fast(zg), oo = hsig(zo);
      c_w = fmaf(ff, c_w, ii * gg);
      h_s[tid] = oo * tanh_fast(c_w);
    }
    __syncthreads();
    // S9: mem update (both layouts, identical math) + fused next scores
    if (t + 1 < LL) {
      const float zr = ee_s[l] * inv;
      v2f S = {0.f, 0.f};
#pragma unroll
      for (int w = 0; w < 32; w++) {
        v2f h2 = *(const v2f*)&h_s[hf * 64 + 2 * w];
        v2f m = Mr[w];
        v2f n = m + (h2 - m) * zr;
        Mr[w] = n;
        S += n * (*(const v2f*)&osN[hf * 64 + 2 * w]);
      }
      float s = S.x + S.y;
      s += __shfl_xor(s, 1);
      if (hf == 0) sc_s[l] = s;
      v2f hc = *(const v2f*)&h_s[2 * dp];
#pragma unroll
      for (int i = 0; i < 32; i++) {
        float zc = ee_s[q * 32 + i] * inv;
        v2f m = Mc[i];
        Mc[i] = m + (hc - m) * zc;
      }
    }
    __syncthreads();
  }

  if (tid < 128) out[b * 128 + tid] = h_s[tid];
}

extern "C" void kernel_launch(void* const* d_in, const int* in_sizes, int n_in,
                              void* d_out, int out_size, void* d_ws, size_t ws_size,
                              hipStream_t stream) {
  const float* x  = (const float*)d_in[0];
  const float* Wr = (const float*)d_in[1];
  const float* Ur = (const float*)d_in[2];
  const float* br = (const float*)d_in[3];
  const float* Ww = (const float*)d_in[4];
  const float* Uw = (const float*)d_in[5];
  const float* bw = (const float*)d_in[6];
  const float* Wc = (const float*)d_in[7];
  const float* bc = (const float*)d_in[8];
  float* out = (float*)d_out;

  // workspace (floats): og 1,048,576 | XW 4,194,304 | OWc 1,048,576 |
  // WrT 65,536 | UrT 65,536 | WwT 65,536 | UwT 65,536 | WcT 32,768
  // total 6,586,368 floats = 26.35 MB
  float* og  = (float*)d_ws;
  float* XW  = og + 1048576;
  float* OWc = XW + 4194304;
  float* WrT = OWc + 1048576;
  float* UrT = WrT + 65536;
  float* WwT = UrT + 65536;
  float* UwT = WwT + 65536;
  float* WcT = UwT + 65536;

  wtrans_kernel<<<128, 512, 0, stream>>>(Wr, WrT, 9);
  wtrans_kernel<<<128, 512, 0, stream>>>(Ur, UrT, 9);
  wtrans_kernel<<<128, 512, 0, stream>>>(Ww, WwT, 9);
  wtrans_kernel<<<128, 512, 0, stream>>>(Uw, UwT, 9);
  wtrans_kernel<<<64, 512, 0, stream>>>(Wc, WcT, 7);
  xw_gemm<<<1024, 512, 0, stream>>>(x, (const float4*)WrT, br, XW);
  reader_kernel<<<32, 512, 0, stream>>>((const float4*)UrT, XW, og);
  owc_gemm<<<1024, 512, 0, stream>>>(og, (const float4*)WcT, bc, OWc);
  writer_kernel<<<32, 512, 0, stream>>>(x, (const float4*)WwT, (const float4*)UwT,
                                        (const float4*)WcT, bw, og, OWc, out);
}

// Round 3
// 2165.625 us; speedup vs baseline: 2.1374x; 2.1374x over previous
//
#include <hip/hip_runtime.h>
#include <stdint.h>

// B=32, L=256, D=128. Reader LSTM scan + attention-memory writer scan. FP32.
// Inputs: x(32,256,128), Wr(128,512), Ur(128,512), br(512),
//         Ww(128,512), Uw(128,512), bw(512), Wc(256,128), bc(128)
// Output: final writer h (32,128) fp32.
//
// v3 structure (v2 minus the register-pressure cliff) — resubmitted after
// round-2 infra failure (container failed twice; kernel never ran):
//   wtrans x5     : transpose weights to float4 k-tiles
//   xw_gemm       : XW[b,t,:] = x[b,t,:]@Wr + br   (parallel, whole chip)
//   reader_kernel : sequential scan, Ur held in registers (32xfloat4/thread),
//                   per step: 1 global load (XW) + LDS h-dot (4 accumulators)
//   owc_gemm      : OWc[b,t,:] = og[b,t,:]@Wc_top + bc (parallel)
//   writer_kernel : per step: softmax, m_rt, m_rt@Wc_bot (L2 loads — NOT
//                   register-held: Mr+Mc already sit at the 256-VGPR cliff),
//                   z-matmul with 4 named accumulator chains, bounded unroll
//                   (<=16 live load regs). v2's WC-in-regs + full unroll
//                   spilled to scratch: WRITE_SIZE 15.3MB/dispatch.
// Workspace: 6,586,368 floats = 26.35 MB.

#define LL 256

typedef float v2f __attribute__((ext_vector_type(2)));

__device__ __forceinline__ float hsig(float x) { return fminf(fmaxf(fmaf(x, 0.2f, 0.5f), 0.f), 1.f); }
__device__ __forceinline__ float tanh_fast(float x) {
  x = fminf(fmaxf(x, -15.f), 15.f);
  float e = __expf(2.f * x);
  return (e - 1.f) / (e + 1.f);
}

// ---- Prep: transpose fp32 W[K][J] (row-major) -> float4 k-tiles ----------
// dst float4 index (k>>2)*J + j holds rows k..k+3 of column j.
__global__ __launch_bounds__(512) void wtrans_kernel(const float* __restrict__ src,
                                                     float* __restrict__ dst, int jshift) {
  int idx = blockIdx.x * 512 + threadIdx.x;
  int J = 1 << jshift;
  int k = idx >> jshift, j = idx & (J - 1);
  dst[(((size_t)(k >> 2) << jshift) + j) * 4 + (k & 3)] = src[idx];
}

// ---- XW = x @ Wr + br, all (b,t) rows in parallel -------------------------
__global__ __launch_bounds__(512) void xw_gemm(const float* __restrict__ x,
                                               const float4* __restrict__ WrT4,
                                               const float* __restrict__ br,
                                               float* __restrict__ XW) {
  alignas(16) __shared__ float xs[8][128];
  const int b = blockIdx.x >> 5, tg = blockIdx.x & 31, tid = threadIdx.x;
  const float* xg = x + ((size_t)b * LL + tg * 8) * 128;
  if (tid < 256) ((float4*)&xs[0][0])[tid] = ((const float4*)xg)[tid];
  __syncthreads();
  float acc[8];
#pragma unroll
  for (int r = 0; r < 8; r++) acc[r] = 0.f;
#pragma unroll 8
  for (int i4 = 0; i4 < 32; i4++) {
    float4 w4 = WrT4[i4 * 512 + tid];
#pragma unroll
    for (int r = 0; r < 8; r++) {
      float4 v = *(const float4*)&xs[r][4 * i4];
      acc[r] += w4.x * v.x + w4.y * v.y + w4.z * v.z + w4.w * v.w;
    }
  }
  const float brj = br[tid];
  float* o = XW + ((size_t)b * LL + tg * 8) * 512;
#pragma unroll
  for (int r = 0; r < 8; r++) o[r * 512 + tid] = acc[r] + brj;
}

// ---- OWc = og @ Wc_top + bc, all (b,t) rows in parallel -------------------
__global__ __launch_bounds__(512) void owc_gemm(const float* __restrict__ og,
                                                const float4* __restrict__ WcT4,
                                                const float* __restrict__ bc,
                                                float* __restrict__ OWc) {
  alignas(16) __shared__ float os[8][128];
  const int b = blockIdx.x >> 5, tg = blockIdx.x & 31, tid = threadIdx.x;
  const int j = tid & 127, r2 = tid >> 7;  // rows r2*2, r2*2+1
  const float* g = og + ((size_t)b * LL + tg * 8) * 128;
  if (tid < 256) ((float4*)&os[0][0])[tid] = ((const float4*)g)[tid];
  __syncthreads();
  float a0 = 0.f, a1 = 0.f;
#pragma unroll 8
  for (int i4 = 0; i4 < 32; i4++) {  // top half of Wc: tiles 0..31
    float4 w4 = WcT4[i4 * 128 + j];
    float4 v0 = *(const float4*)&os[r2 * 2][4 * i4];
    float4 v1 = *(const float4*)&os[r2 * 2 + 1][4 * i4];
    a0 += w4.x * v0.x + w4.y * v0.y + w4.z * v0.z + w4.w * v0.w;
    a1 += w4.x * v1.x + w4.y * v1.y + w4.z * v1.z + w4.w * v1.w;
  }
  const float bcj = bc[j];
  float* o = OWc + ((size_t)b * LL + tg * 8) * 128;
  o[(r2 * 2) * 128 + j] = a0 + bcj;
  o[(r2 * 2 + 1) * 128 + j] = a1 + bcj;
}

// ---- Reader: sequential LSTM scan, Ur register-resident -------------------
__global__ __launch_bounds__(512, 2) void reader_kernel(const float4* __restrict__ UrT4,
                                                        const float* __restrict__ XW,
                                                        float* __restrict__ og) {
  alignas(16) __shared__ float h_s[128];
  alignas(16) __shared__ float pp_s[512];
  const int b = blockIdx.x, tid = threadIdx.x;
  const float* XWb = XW + (size_t)b * LL * 512;
  float* ogb = og + (size_t)b * LL * 128;

  float4 U[32];  // column tid of Ur, held for the whole scan (128 VGPRs)
#pragma unroll
  for (int i4 = 0; i4 < 32; i4++) U[i4] = UrT4[i4 * 512 + tid];

  float c_r = 0.f;
  if (tid < 128) h_s[tid] = 0.f;
  float xwv = XWb[tid];  // z-row for t=0 (x@Wr + br precomputed)
  __syncthreads();

  for (int t = 0; t < LL; t++) {
    float xw_n = (t + 1 < LL) ? XWb[(t + 1) * 512 + tid] : 0.f;  // prefetch
    v2f acc[4] = {{0.f, 0.f}, {0.f, 0.f}, {0.f, 0.f}, {0.f, 0.f}};
#pragma unroll
    for (int i4 = 0; i4 < 32; i4++) {  // full unroll: U[i4] must stay static
      float4 v = *(const float4*)&h_s[4 * i4];
      float4 w = U[i4];
      acc[i4 & 3] += (v2f){w.x, w.y} * (v2f){v.x, v.y};
      acc[i4 & 3] += (v2f){w.z, w.w} * (v2f){v.z, v.w};
    }
    v2f A = (acc[0] + acc[1]) + (acc[2] + acc[3]);
    pp_s[tid] = A.x + A.y + xwv;
    __syncthreads();
    if (tid < 128) {
      float zi = pp_s[tid], zf = pp_s[128 + tid], zg = pp_s[256 + tid], zo = pp_s[384 + tid];
      float ii = hsig(zi), ff = hsig(zf), gg = tanh_fast(zg), oo = hsig(zo);
      c_r = fmaf(ff, c_r, ii * gg);
      float h = oo * tanh_fast(c_r);
      h_s[tid] = h;
      ogb[t * 128 + tid] = h;
    }
    __syncthreads();
    xwv = xw_n;
  }
}

// ---- Writer: attention-memory scan ---------------------------------------
__global__ __launch_bounds__(512, 2) void writer_kernel(
    const float* __restrict__ x,
    const float4* __restrict__ WwT4, const float4* __restrict__ UwT4,
    const float4* __restrict__ WcT4,
    const float* __restrict__ bw,
    const float* __restrict__ og, const float* __restrict__ OWc,
    float* __restrict__ out) {
  alignas(16) __shared__ float h_s[128];
  alignas(16) __shared__ float osN[128];   // o_{t+1} (o_0 during prologue)
  alignas(16) __shared__ float ow_s[128];  // OWc row t
  alignas(16) __shared__ float sc_s[256], ee_s[256];
  alignas(16) __shared__ float mr_s[128], ct_s[128];
  alignas(16) __shared__ float pp_s[1024];
  __shared__ float rr_s[16];

  const int b = blockIdx.x, tid = threadIdx.x;
  const int lane = tid & 63, wv = tid >> 6;
  const int l = tid >> 1, hf = tid & 1;    // row-major role
  const int q = tid >> 6, dp = tid & 63;   // col-major role
  const int jj = tid & 127, kq = tid >> 7; // S5 role

  const float* xg = x + (size_t)b * (LL * 128);
  const float* ogb = og + (size_t)b * (LL * 128);
  const float* owb = OWc + (size_t)b * (LL * 128);

  // register-resident mem, two layouts (fp32 pairs) — 128 VGPRs, AT the cliff.
  v2f Mr[32], Mc[32];
#pragma unroll
  for (int w = 0; w < 32; w++) Mr[w] = *(const v2f*)(xg + l * 128 + hf * 64 + 2 * w);
#pragma unroll
  for (int i = 0; i < 32; i++) Mc[i] = *(const v2f*)(xg + (q * 32 + i) * 128 + 2 * dp);

  const float bwj = bw[tid];

  float c_w = 0.f;
  if (tid < 128) { h_s[tid] = 0.f; osN[tid] = ogb[tid]; }
  __syncthreads();
  { // prologue: sc_s[l] = mem0[l] . o_0
    v2f S = {0.f, 0.f};
#pragma unroll
    for (int w = 0; w < 32; w++) S += Mr[w] * (*(const v2f*)&osN[hf * 64 + 2 * w]);
    float s = S.x + S.y;
    s += __shfl_xor(s, 1);
    if (hf == 0) sc_s[l] = s;
  }
  __syncthreads();

  for (int t = 0; t < LL; t++) {
    // S1: load o_{t+1} + OWc row t; softmax max
    if (tid >= 128 && tid < 256) {
      if (t + 1 < LL) osN[tid - 128] = ogb[(t + 1) * 128 + (tid - 128)];
    } else if (tid >= 256 && tid < 384) {
      ow_s[tid - 256] = owb[t * 128 + (tid - 256)];
    }
    if (tid < 256) {
      float m = sc_s[tid];
#pragma unroll
      for (int off = 32; off > 0; off >>= 1) m = fmaxf(m, __shfl_xor(m, off));
      if (lane == 0) rr_s[wv] = m;
    }
    __syncthreads();
    // S2: exp + sum
    if (tid < 256) {
      float mx = fmaxf(fmaxf(rr_s[0], rr_s[1]), fmaxf(rr_s[2], rr_s[3]));
      float e = __expf(sc_s[tid] - mx);
      ee_s[tid] = e;
      float s2 = e;
#pragma unroll
      for (int off = 32; off > 0; off >>= 1) s2 += __shfl_xor(s2, off);
      if (lane == 0) rr_s[8 + wv] = s2;
    }
    __syncthreads();
    const float inv = 1.f / (rr_s[8] + rr_s[9] + rr_s[10] + rr_s[11]);
    // S3: m_rt partials (col-major, register-local)
    {
      v2f P = {0.f, 0.f};
#pragma unroll
      for (int i = 0; i < 32; i++) P += Mc[i] * ee_s[q * 32 + i];
      *(v2f*)&pp_s[q * 128 + 2 * dp] = P;
    }
    __syncthreads();
    // S4: m_rt final
    if (tid < 128) {
      float s = 0.f;
#pragma unroll
      for (int g = 0; g < 8; g++) s += pp_s[g * 128 + tid];
      mr_s[tid] = s * inv;
    }
    __syncthreads();
    // S5: c_t partials = m_rt @ Wc_bot (L2-resident loads; NOT register-held)
    {
      v2f A = {0.f, 0.f};
#pragma unroll 4
      for (int i8 = 0; i8 < 8; i8++) {
        float4 w4 = WcT4[(size_t)(32 + kq * 8 + i8) * 128 + jj];
        float4 v4 = *(const float4*)&mr_s[kq * 32 + 4 * i8];
        A += (v2f){w4.x, w4.y} * (v2f){v4.x, v4.y};
        A += (v2f){w4.z, w4.w} * (v2f){v4.z, v4.w};
      }
      pp_s[kq * 128 + jj] = A.x + A.y;
    }
    __syncthreads();
    // S6: c_t final
    if (tid < 128)
      ct_s[tid] = ow_s[tid] + pp_s[tid] + pp_s[128 + tid] + pp_s[256 + tid] + pp_s[384 + tid];
    __syncthreads();
    // S7: z[j] = ct@Ww + h@Uw + bw — 4 named accumulator chains,
    // bounded unroll (<=16 live load regs), static acc indexing.
    {
      v2f a0 = {0.f, 0.f}, a1 = {0.f, 0.f}, a2 = {0.f, 0.f}, a3 = {0.f, 0.f};
#pragma unroll 2
      for (int o = 0; o < 8; o++) {
        float4 w0 = WwT4[(o * 4 + 0) * 512 + tid]; float4 x0 = *(const float4*)&ct_s[16 * o + 0];
        float4 w1 = WwT4[(o * 4 + 1) * 512 + tid]; float4 x1 = *(const float4*)&ct_s[16 * o + 4];
        float4 w2 = WwT4[(o * 4 + 2) * 512 + tid]; float4 x2 = *(const float4*)&ct_s[16 * o + 8];
        float4 w3 = WwT4[(o * 4 + 3) * 512 + tid]; float4 x3 = *(const float4*)&ct_s[16 * o + 12];
        a0 += (v2f){w0.x, w0.y} * (v2f){x0.x, x0.y}; a0 += (v2f){w0.z, w0.w} * (v2f){x0.z, x0.w};
        a1 += (v2f){w1.x, w1.y} * (v2f){x1.x, x1.y}; a1 += (v2f){w1.z, w1.w} * (v2f){x1.z, x1.w};
        a2 += (v2f){w2.x, w2.y} * (v2f){x2.x, x2.y}; a2 += (v2f){w2.z, w2.w} * (v2f){x2.z, x2.w};
        a3 += (v2f){w3.x, w3.y} * (v2f){x3.x, x3.y}; a3 += (v2f){w3.z, w3.w} * (v2f){x3.z, x3.w};
      }
#pragma unroll 2
      for (int o = 0; o < 8; o++) {
        float4 w0 = UwT4[(o * 4 + 0) * 512 + tid]; float4 x0 = *(const float4*)&h_s[16 * o + 0];
        float4 w1 = UwT4[(o * 4 + 1) * 512 + tid]; float4 x1 = *(const float4*)&h_s[16 * o + 4];
        float4 w2 = UwT4[(o * 4 + 2) * 512 + tid]; float4 x2 = *(const float4*)&h_s[16 * o + 8];
        float4 w3 = UwT4[(o * 4 + 3) * 512 + tid]; float4 x3 = *(const float4*)&h_s[16 * o + 12];
        a0 += (v2f){w0.x, w0.y} * (v2f){x0.x, x0.y}; a0 += (v2f){w0.z, w0.w} * (v2f){x0.z, x0.w};
        a1 += (v2f){w1.x, w1.y} * (v2f){x1.x, x1.y}; a1 += (v2f){w1.z, w1.w} * (v2f){x1.z, x1.w};
        a2 += (v2f){w2.x, w2.y} * (v2f){x2.x, x2.y}; a2 += (v2f){w2.z, w2.w} * (v2f){x2.z, x2.w};
        a3 += (v2f){w3.x, w3.y} * (v2f){x3.x, x3.y}; a3 += (v2f){w3.z, w3.w} * (v2f){x3.z, x3.w};
      }
      v2f A = (a0 + a1) + (a2 + a3);
      pp_s[tid] = A.x + A.y + bwj;
    }
    __syncthreads();
    // S8: gates
    if (tid < 128) {
      float zi = pp_s[tid], zf = pp_s[128 + tid], zg = pp_s[256 + tid], zo = pp_s[384 + tid];
      float ii = hsig(zi), ff = hsig(zf), gg = tanh_fast(zg), oo = hsig(zo);
      c_w = fmaf(ff, c_w, ii * gg);
      h_s[tid] = oo * tanh_fast(c_w);
    }
    __syncthreads();
    // S9: mem update (both layouts, identical math) + fused next scores
    if (t + 1 < LL) {
      const float zr = ee_s[l] * inv;
      v2f S = {0.f, 0.f};
#pragma unroll
      for (int w = 0; w < 32; w++) {
        v2f h2 = *(const v2f*)&h_s[hf * 64 + 2 * w];
        v2f m = Mr[w];
        v2f n = m + (h2 - m) * zr;
        Mr[w] = n;
        S += n * (*(const v2f*)&osN[hf * 64 + 2 * w]);
      }
      float s = S.x + S.y;
      s += __shfl_xor(s, 1);
      if (hf == 0) sc_s[l] = s;
      v2f hc = *(const v2f*)&h_s[2 * dp];
#pragma unroll
      for (int i = 0; i < 32; i++) {
        float zc = ee_s[q * 32 + i] * inv;
        v2f m = Mc[i];
        Mc[i] = m + (hc - m) * zc;
      }
    }
    __syncthreads();
  }

  if (tid < 128) out[b * 128 + tid] = h_s[tid];
}

extern "C" void kernel_launch(void* const* d_in, const int* in_sizes, int n_in,
                              void* d_out, int out_size, void* d_ws, size_t ws_size,
                              hipStream_t stream) {
  const float* x  = (const float*)d_in[0];
  const float* Wr = (const float*)d_in[1];
  const float* Ur = (const float*)d_in[2];
  const float* br = (const float*)d_in[3];
  const float* Ww = (const float*)d_in[4];
  const float* Uw = (const float*)d_in[5];
  const float* bw = (const float*)d_in[6];
  const float* Wc = (const float*)d_in[7];
  const float* bc = (const float*)d_in[8];
  float* out = (float*)d_out;

  // workspace (floats): og 1,048,576 | XW 4,194,304 | OWc 1,048,576 |
  // WrT 65,536 | UrT 65,536 | WwT 65,536 | UwT 65,536 | WcT 32,768
  // total 6,586,368 floats = 26.35 MB
  float* og  = (float*)d_ws;
  float* XW  = og + 1048576;
  float* OWc = XW + 4194304;
  float* WrT = OWc + 1048576;
  float* UrT = WrT + 65536;
  float* WwT = UrT + 65536;
  float* UwT = WwT + 65536;
  float* WcT = UwT + 65536;

  wtrans_kernel<<<128, 512, 0, stream>>>(Wr, WrT, 9);
  wtrans_kernel<<<128, 512, 0, stream>>>(Ur, UrT, 9);
  wtrans_kernel<<<128, 512, 0, stream>>>(Ww, WwT, 9);
  wtrans_kernel<<<128, 512, 0, stream>>>(Uw, UwT, 9);
  wtrans_kernel<<<64, 512, 0, stream>>>(Wc, WcT, 7);
  xw_gemm<<<1024, 512, 0, stream>>>(x, (const float4*)WrT, br, XW);
  reader_kernel<<<32, 512, 0, stream>>>((const float4*)UrT, XW, og);
  owc_gemm<<<1024, 512, 0, stream>>>(og, (const float4*)WcT, bc, OWc);
  writer_kernel<<<32, 512, 0, stream>>>(x, (const float4*)WwT, (const float4*)UwT,
                                        (const float4*)WcT, bw, og, OWc, out);
}

// Round 4
// 1905.488 us; speedup vs baseline: 2.4292x; 1.1365x over previous
//
#include <hip/hip_runtime.h>
#include <stdint.h>

// B=32, L=256, D=128. Reader LSTM scan + attention-memory writer scan. FP32.
// Inputs: x(32,256,128), Wr(128,512), Ur(128,512), br(512),
//         Ww(128,512), Uw(128,512), bw(512), Wc(256,128), bc(128)
// Output: final writer h (32,128) fp32.
//
// v4: writer is per-CU L2-BW-bound on weight streaming (512KB Ww+Uw + 64KB Wc
// per step ~= 3.8us of the 7.25us step). Two fixes, both fp32-exact:
//  (a) algebra: z = ct@Ww + h@Uw,  ct = o@Wc_top + m_rt@Wc_bot + bc
//      => z = ZW_t + m_rt@Vw + h@Uw   with  Vw = Wc_bot@Ww  (precomputed) and
//         ZW = og@(Wc_top@Ww) + (bc@Ww + bw)  (parallel GEMM after reader).
//      Deletes old S5/S6 (2 barriers + Wc traffic + ow_s staging).
//  (b) Uw LDS-cache: 1 block/CU owns 160KB LDS; stage 18/32 of Uw's k-tiles
//      (144KB) once, read from LDS per step. Per-step L2 traffic 576->368KB.
//      Big-LDS via hipFuncSetAttribute (capture-safe; NC=6/48KB fallback).
// Workspace: 5.70M floats = 22.8MB (ZW aliases XW; XW dead after reader).

#define LL 256

typedef float v2f __attribute__((ext_vector_type(2)));

__device__ __forceinline__ float hsig(float x) { return fminf(fmaxf(fmaf(x, 0.2f, 0.5f), 0.f), 1.f); }
__device__ __forceinline__ float tanh_fast(float x) {
  x = fminf(fmaxf(x, -15.f), 15.f);
  float e = __expf(2.f * x);
  return (e - 1.f) / (e + 1.f);
}

// ---- Prep: transpose fp32 W[K][J] (row-major) -> float4 k-tiles ----------
// dst float4 index (k>>2)*J + j holds rows k..k+3 of column j.
__global__ __launch_bounds__(512) void wtrans_kernel(const float* __restrict__ src,
                                                     float* __restrict__ dst, int jshift) {
  int idx = blockIdx.x * 512 + threadIdx.x;
  int J = 1 << jshift;
  int k = idx >> jshift, j = idx & (J - 1);
  dst[(((size_t)(k >> 2) << jshift) + j) * 4 + (k & 3)] = src[idx];
}

// ---- PVw[r][j] = Wc[r][:] @ Ww[:,j]  (r<128: Pw=Wc_top@Ww, r>=128: Vw) ----
__global__ __launch_bounds__(512) void pvw_gemm(const float* __restrict__ Wc,
                                                const float* __restrict__ Ww,
                                                float* __restrict__ PVw) {
  __shared__ float wrow[128];
  const int r = blockIdx.x, j = threadIdx.x;
  if (j < 128) wrow[j] = Wc[r * 128 + j];
  __syncthreads();
  float a = 0.f;
#pragma unroll 4
  for (int m = 0; m < 128; m++) a = fmaf(wrow[m], Ww[m * 512 + j], a);
  PVw[r * 512 + j] = a;
}

// ---- pz[j] = bc @ Ww[:,j] + bw[j] -----------------------------------------
__global__ __launch_bounds__(512) void pz_kernel(const float* __restrict__ bc,
                                                 const float* __restrict__ Ww,
                                                 const float* __restrict__ bw,
                                                 float* __restrict__ pz) {
  __shared__ float b_s[128];
  const int j = threadIdx.x;
  if (j < 128) b_s[j] = bc[j];
  __syncthreads();
  float a = bw[j];
#pragma unroll 4
  for (int m = 0; m < 128; m++) a = fmaf(b_s[m], Ww[m * 512 + j], a);
  pz[j] = a;
}

// ---- GEMM: OUT[b,t,:] = IN[b,t,:] @ W(T4 tiles, K=128,J=512) + bias -------
// Used for XW = x@Wr + br  and  ZW = og@Pw + pz.
__global__ __launch_bounds__(512) void xw_gemm(const float* __restrict__ x,
                                               const float4* __restrict__ WrT4,
                                               const float* __restrict__ br,
                                               float* __restrict__ XW) {
  alignas(16) __shared__ float xs[8][128];
  const int b = blockIdx.x >> 5, tg = blockIdx.x & 31, tid = threadIdx.x;
  const float* xg = x + ((size_t)b * LL + tg * 8) * 128;
  if (tid < 256) ((float4*)&xs[0][0])[tid] = ((const float4*)xg)[tid];
  __syncthreads();
  float acc[8];
#pragma unroll
  for (int r = 0; r < 8; r++) acc[r] = 0.f;
#pragma unroll 8
  for (int i4 = 0; i4 < 32; i4++) {
    float4 w4 = WrT4[i4 * 512 + tid];
#pragma unroll
    for (int r = 0; r < 8; r++) {
      float4 v = *(const float4*)&xs[r][4 * i4];
      acc[r] += w4.x * v.x + w4.y * v.y + w4.z * v.z + w4.w * v.w;
    }
  }
  const float brj = br[tid];
  float* o = XW + ((size_t)b * LL + tg * 8) * 512;
#pragma unroll
  for (int r = 0; r < 8; r++) o[r * 512 + tid] = acc[r] + brj;
}

// ---- Reader: sequential LSTM scan, Ur register-resident -------------------
__global__ __launch_bounds__(512, 2) void reader_kernel(const float4* __restrict__ UrT4,
                                                        const float* __restrict__ XW,
                                                        float* __restrict__ og) {
  alignas(16) __shared__ float h_s[128];
  alignas(16) __shared__ float pp_s[512];
  const int b = blockIdx.x, tid = threadIdx.x;
  const float* XWb = XW + (size_t)b * LL * 512;
  float* ogb = og + (size_t)b * LL * 128;

  float4 U[32];  // column tid of Ur, held for the whole scan (128 VGPRs)
#pragma unroll
  for (int i4 = 0; i4 < 32; i4++) U[i4] = UrT4[i4 * 512 + tid];

  float c_r = 0.f;
  if (tid < 128) h_s[tid] = 0.f;
  float xwv = XWb[tid];  // z-row for t=0 (x@Wr + br precomputed)
  __syncthreads();

  for (int t = 0; t < LL; t++) {
    float xw_n = (t + 1 < LL) ? XWb[(t + 1) * 512 + tid] : 0.f;  // prefetch
    v2f acc[4] = {{0.f, 0.f}, {0.f, 0.f}, {0.f, 0.f}, {0.f, 0.f}};
#pragma unroll
    for (int i4 = 0; i4 < 32; i4++) {  // full unroll: U[i4] must stay static
      float4 v = *(const float4*)&h_s[4 * i4];
      float4 w = U[i4];
      acc[i4 & 3] += (v2f){w.x, w.y} * (v2f){v.x, v.y};
      acc[i4 & 3] += (v2f){w.z, w.w} * (v2f){v.z, v.w};
    }
    v2f A = (acc[0] + acc[1]) + (acc[2] + acc[3]);
    pp_s[tid] = A.x + A.y + xwv;
    __syncthreads();
    if (tid < 128) {
      float zi = pp_s[tid], zf = pp_s[128 + tid], zg = pp_s[256 + tid], zo = pp_s[384 + tid];
      float ii = hsig(zi), ff = hsig(zf), gg = tanh_fast(zg), oo = hsig(zo);
      c_r = fmaf(ff, c_r, ii * gg);
      float h = oo * tanh_fast(c_r);
      h_s[tid] = h;
      ogb[t * 128 + tid] = h;
    }
    __syncthreads();
    xwv = xw_n;
  }
}

// ---- Writer: attention-memory scan ---------------------------------------
// z = ZW_t + m_rt@Vw + h@Uw; Uw tiles [0,NC) served from LDS, rest from L2.
__global__ __launch_bounds__(512, 2) void writer_kernel(
    const float* __restrict__ x,
    const float4* __restrict__ VwT4, const float4* __restrict__ UwT4,
    const float* __restrict__ og, const float* __restrict__ ZW,
    float* __restrict__ out, const int NC) {
  alignas(16) __shared__ float h_s[128];
  alignas(16) __shared__ float osN[128];   // o_{t+1} (o_0 during prologue)
  alignas(16) __shared__ float sc_s[256], ee_s[256];
  alignas(16) __shared__ float mr_s[128];
  alignas(16) __shared__ float pp_s[1024];
  __shared__ float rr_s[16];
  extern __shared__ float4 UwL[];          // NC*512 float4 Uw k-tile cache

  const int b = blockIdx.x, tid = threadIdx.x;
  const int lane = tid & 63, wv = tid >> 6;
  const int l = tid >> 1, hf = tid & 1;    // row-major role
  const int q = tid >> 6, dp = tid & 63;   // col-major role

  const float* xg = x + (size_t)b * (LL * 128);
  const float* ogb = og + (size_t)b * (LL * 128);
  const float* ZWb = ZW + (size_t)b * (LL * 512);

  // stage Uw k-tiles [0,NC) into LDS once (144KB at NC=18)
  for (int i = tid; i < NC * 512; i += 512) UwL[i] = UwT4[i];

  // register-resident mem, two layouts (fp32 pairs) — 128 VGPRs, AT the cliff.
  v2f Mr[32], Mc[32];
#pragma unroll
  for (int w = 0; w < 32; w++) Mr[w] = *(const v2f*)(xg + l * 128 + hf * 64 + 2 * w);
#pragma unroll
  for (int i = 0; i < 32; i++) Mc[i] = *(const v2f*)(xg + (q * 32 + i) * 128 + 2 * dp);

  float c_w = 0.f;
  if (tid < 128) { h_s[tid] = 0.f; osN[tid] = ogb[tid]; }
  __syncthreads();
  { // prologue: sc_s[l] = mem0[l] . o_0
    v2f S = {0.f, 0.f};
#pragma unroll
    for (int w = 0; w < 32; w++) S += Mr[w] * (*(const v2f*)&osN[hf * 64 + 2 * w]);
    float s = S.x + S.y;
    s += __shfl_xor(s, 1);
    if (hf == 0) sc_s[l] = s;
  }
  __syncthreads();

  for (int t = 0; t < LL; t++) {
    float zwv = ZWb[(size_t)t * 512 + tid];  // issue early; used in S5'
    // S1: load o_{t+1}; softmax max
    if (tid >= 128 && tid < 256 && t + 1 < LL)
      osN[tid - 128] = ogb[(t + 1) * 128 + (tid - 128)];
    if (tid < 256) {
      float m = sc_s[tid];
#pragma unroll
      for (int off = 32; off > 0; off >>= 1) m = fmaxf(m, __shfl_xor(m, off));
      if (lane == 0) rr_s[wv] = m;
    }
    __syncthreads();
    // S2: exp + sum
    if (tid < 256) {
      float mx = fmaxf(fmaxf(rr_s[0], rr_s[1]), fmaxf(rr_s[2], rr_s[3]));
      float e = __expf(sc_s[tid] - mx);
      ee_s[tid] = e;
      float s2 = e;
#pragma unroll
      for (int off = 32; off > 0; off >>= 1) s2 += __shfl_xor(s2, off);
      if (lane == 0) rr_s[8 + wv] = s2;
    }
    __syncthreads();
    const float inv = 1.f / (rr_s[8] + rr_s[9] + rr_s[10] + rr_s[11]);
    // S3: m_rt partials (col-major, register-local)
    {
      v2f P = {0.f, 0.f};
#pragma unroll
      for (int i = 0; i < 32; i++) P += Mc[i] * ee_s[q * 32 + i];
      *(v2f*)&pp_s[q * 128 + 2 * dp] = P;
    }
    __syncthreads();
    // S4: m_rt final
    if (tid < 128) {
      float s = 0.f;
#pragma unroll
      for (int g = 0; g < 8; g++) s += pp_s[g * 128 + tid];
      mr_s[tid] = s * inv;
    }
    __syncthreads();
    // S5': z[j] = ZW_t[j] + m_rt@Vw + h@Uw — 4 named acc chains; Uw tiles
    // [0,NC) from LDS, [NC,32) from L2. NC even; bounded unroll.
    {
      v2f a0 = {0.f, 0.f}, a1 = {0.f, 0.f}, a2 = {0.f, 0.f}, a3 = {0.f, 0.f};
#pragma unroll 2
      for (int i4 = 0; i4 < 32; i4 += 2) {  // Vw (L2)
        float4 w0 = VwT4[i4 * 512 + tid];
        float4 w1 = VwT4[(i4 + 1) * 512 + tid];
        float4 v0 = *(const float4*)&mr_s[4 * i4];
        float4 v1 = *(const float4*)&mr_s[4 * i4 + 4];
        a0 += (v2f){w0.x, w0.y} * (v2f){v0.x, v0.y};
        a0 += (v2f){w0.z, w0.w} * (v2f){v0.z, v0.w};
        a1 += (v2f){w1.x, w1.y} * (v2f){v1.x, v1.y};
        a1 += (v2f){w1.z, w1.w} * (v2f){v1.z, v1.w};
      }
#pragma unroll 2
      for (int i4 = 0; i4 < NC; i4 += 2) {  // Uw (LDS cache)
        float4 w0 = UwL[i4 * 512 + tid];
        float4 w1 = UwL[(i4 + 1) * 512 + tid];
        float4 v0 = *(const float4*)&h_s[4 * i4];
        float4 v1 = *(const float4*)&h_s[4 * i4 + 4];
        a2 += (v2f){w0.x, w0.y} * (v2f){v0.x, v0.y};
        a2 += (v2f){w0.z, w0.w} * (v2f){v0.z, v0.w};
        a3 += (v2f){w1.x, w1.y} * (v2f){v1.x, v1.y};
        a3 += (v2f){w1.z, w1.w} * (v2f){v1.z, v1.w};
      }
#pragma unroll 2
      for (int i4 = NC; i4 < 32; i4 += 2) {  // Uw remainder (L2)
        float4 w0 = UwT4[i4 * 512 + tid];
        float4 w1 = UwT4[(i4 + 1) * 512 + tid];
        float4 v0 = *(const float4*)&h_s[4 * i4];
        float4 v1 = *(const float4*)&h_s[4 * i4 + 4];
        a0 += (v2f){w0.x, w0.y} * (v2f){v0.x, v0.y};
        a0 += (v2f){w0.z, w0.w} * (v2f){v0.z, v0.w};
        a1 += (v2f){w1.x, w1.y} * (v2f){v1.x, v1.y};
        a1 += (v2f){w1.z, w1.w} * (v2f){v1.z, v1.w};
      }
      v2f A = (a0 + a2) + (a1 + a3);
      pp_s[tid] = A.x + A.y + zwv;
    }
    __syncthreads();
    // S6': gates
    if (tid < 128) {
      float zi = pp_s[tid], zf = pp_s[128 + tid], zg = pp_s[256 + tid], zo = pp_s[384 + tid];
      float ii = hsig(zi), ff = hsig(zf), gg = tanh_fast(zg), oo = hsig(zo);
      c_w = fmaf(ff, c_w, ii * gg);
      h_s[tid] = oo * tanh_fast(c_w);
    }
    __syncthreads();
    // S7': mem update (both layouts, identical math) + fused next scores
    if (t + 1 < LL) {
      const float zr = ee_s[l] * inv;
      v2f S = {0.f, 0.f};
#pragma unroll
      for (int w = 0; w < 32; w++) {
        v2f h2 = *(const v2f*)&h_s[hf * 64 + 2 * w];
        v2f m = Mr[w];
        v2f n = m + (h2 - m) * zr;
        Mr[w] = n;
        S += n * (*(const v2f*)&osN[hf * 64 + 2 * w]);
      }
      float s = S.x + S.y;
      s += __shfl_xor(s, 1);
      if (hf == 0) sc_s[l] = s;
      v2f hc = *(const v2f*)&h_s[2 * dp];
#pragma unroll
      for (int i = 0; i < 32; i++) {
        float zc = ee_s[q * 32 + i] * inv;
        v2f m = Mc[i];
        Mc[i] = m + (hc - m) * zc;
      }
    }
    __syncthreads();
  }

  if (tid < 128) out[b * 128 + tid] = h_s[tid];
}

extern "C" void kernel_launch(void* const* d_in, const int* in_sizes, int n_in,
                              void* d_out, int out_size, void* d_ws, size_t ws_size,
                              hipStream_t stream) {
  const float* x  = (const float*)d_in[0];
  const float* Wr = (const float*)d_in[1];
  const float* Ur = (const float*)d_in[2];
  const float* br = (const float*)d_in[3];
  const float* Ww = (const float*)d_in[4];
  const float* Uw = (const float*)d_in[5];
  const float* bw = (const float*)d_in[6];
  const float* Wc = (const float*)d_in[7];
  const float* bc = (const float*)d_in[8];
  float* out = (float*)d_out;

  // workspace (floats): og 1,048,576 | XW/ZW 4,194,304 | WrT 65,536 |
  // UrT 65,536 | UwT 65,536 | PVw 131,072 | PwT 65,536 | VwT 65,536 | pz 512
  // total 5,702,656 floats = 22.8 MB
  float* og  = (float*)d_ws;
  float* XW  = og + 1048576;   // ZW aliases XW (XW dead after reader)
  float* WrT = XW + 4194304;
  float* UrT = WrT + 65536;
  float* UwT = UrT + 65536;
  float* PVw = UwT + 65536;
  float* PwT = PVw + 131072;
  float* VwT = PwT + 65536;
  float* pz  = VwT + 65536;

  // big-LDS opt-in for the Uw cache (capture-safe: not a stream op).
  static int nc_cached = -1;
  if (nc_cached < 0) {
    int want = 18 * 512 * (int)sizeof(float4);  // 147456 B dynamic
    nc_cached = (hipFuncSetAttribute((const void*)writer_kernel,
                                     hipFuncAttributeMaxDynamicSharedMemorySize,
                                     want) == hipSuccess)
                    ? 18
                    : 6;  // fallback: 48KB dynamic, under default 64KB limit
  }
  const int NC = nc_cached;
  const size_t shbytes = (size_t)NC * 512 * sizeof(float4);

  wtrans_kernel<<<128, 512, 0, stream>>>(Wr, WrT, 9);
  wtrans_kernel<<<128, 512, 0, stream>>>(Ur, UrT, 9);
  wtrans_kernel<<<128, 512, 0, stream>>>(Uw, UwT, 9);
  pvw_gemm<<<256, 512, 0, stream>>>(Wc, Ww, PVw);
  pz_kernel<<<1, 512, 0, stream>>>(bc, Ww, bw, pz);
  wtrans_kernel<<<128, 512, 0, stream>>>(PVw, PwT, 9);
  wtrans_kernel<<<128, 512, 0, stream>>>(PVw + 65536, VwT, 9);
  xw_gemm<<<1024, 512, 0, stream>>>(x, (const float4*)WrT, br, XW);
  reader_kernel<<<32, 512, 0, stream>>>((const float4*)UrT, XW, og);
  xw_gemm<<<1024, 512, 0, stream>>>(og, (const float4*)PwT, pz, XW);  // ZW
  writer_kernel<<<32, 512, shbytes, stream>>>(x, (const float4*)VwT,
                                              (const float4*)UwT, og, XW, out, NC);
}

// Round 5
// 1883.899 us; speedup vs baseline: 2.4571x; 1.0115x over previous
//
#include <hip/hip_runtime.h>
#include <stdint.h>

// B=32, L=256, D=128. Reader LSTM scan + attention-memory writer scan. FP32.
// Inputs: x(32,256,128), Wr(128,512), Ur(128,512), br(512),
//         Ww(128,512), Uw(128,512), bw(512), Wc(256,128), bc(128)
// Output: final writer h (32,128) fp32.
//
// v5: writer is per-CU L2-BW-bound on weight streaming (v4 streamed ~370KB/
// step: 32 Vw tiles + 14 uncached Uw tiles). Two changes:
//  (a) 16 Vw k-tiles held in REGISTERS (64 VGPRs; persistent total 192 —
//      Mr64+Mc64+VR64; v4 ran VGPR=104 with zero scratch, so headroom).
//      Streamed bytes/step: 370 -> 242 KB.
//  (b) h@Uw hoisted to the TOP of the step: S5's h is h_{t-1} (gates write
//      h_s after S5), so the Uw matvec (18 LDS tiles + 14 L2 tiles) overlaps
//      the softmax stages S1-S4 instead of serializing in S5's interval.
//  NC (Uw tiles cached in LDS) is now a template param (18, 6-fallback) so
//  every loop has static bounds.
// Workspace: 5.70M floats = 22.8MB (ZW aliases XW; XW dead after reader).

#define LL 256

typedef float v2f __attribute__((ext_vector_type(2)));

__device__ __forceinline__ float hsig(float x) { return fminf(fmaxf(fmaf(x, 0.2f, 0.5f), 0.f), 1.f); }
__device__ __forceinline__ float tanh_fast(float x) {
  x = fminf(fmaxf(x, -15.f), 15.f);
  float e = __expf(2.f * x);
  return (e - 1.f) / (e + 1.f);
}

// ---- Prep: transpose fp32 W[K][J] (row-major) -> float4 k-tiles ----------
// dst float4 index (k>>2)*J + j holds rows k..k+3 of column j.
__global__ __launch_bounds__(512) void wtrans_kernel(const float* __restrict__ src,
                                                     float* __restrict__ dst, int jshift) {
  int idx = blockIdx.x * 512 + threadIdx.x;
  int J = 1 << jshift;
  int k = idx >> jshift, j = idx & (J - 1);
  dst[(((size_t)(k >> 2) << jshift) + j) * 4 + (k & 3)] = src[idx];
}

// ---- PVw[r][j] = Wc[r][:] @ Ww[:,j]  (r<128: Pw=Wc_top@Ww, r>=128: Vw) ----
__global__ __launch_bounds__(512) void pvw_gemm(const float* __restrict__ Wc,
                                                const float* __restrict__ Ww,
                                                float* __restrict__ PVw) {
  __shared__ float wrow[128];
  const int r = blockIdx.x, j = threadIdx.x;
  if (j < 128) wrow[j] = Wc[r * 128 + j];
  __syncthreads();
  float a = 0.f;
#pragma unroll 4
  for (int m = 0; m < 128; m++) a = fmaf(wrow[m], Ww[m * 512 + j], a);
  PVw[r * 512 + j] = a;
}

// ---- pz[j] = bc @ Ww[:,j] + bw[j] -----------------------------------------
__global__ __launch_bounds__(512) void pz_kernel(const float* __restrict__ bc,
                                                 const float* __restrict__ Ww,
                                                 const float* __restrict__ bw,
                                                 float* __restrict__ pz) {
  __shared__ float b_s[128];
  const int j = threadIdx.x;
  if (j < 128) b_s[j] = bc[j];
  __syncthreads();
  float a = bw[j];
#pragma unroll 4
  for (int m = 0; m < 128; m++) a = fmaf(b_s[m], Ww[m * 512 + j], a);
  pz[j] = a;
}

// ---- GEMM: OUT[b,t,:] = IN[b,t,:] @ W(T4 tiles, K=128,J=512) + bias -------
// Used for XW = x@Wr + br  and  ZW = og@Pw + pz.
__global__ __launch_bounds__(512) void xw_gemm(const float* __restrict__ x,
                                               const float4* __restrict__ WrT4,
                                               const float* __restrict__ br,
                                               float* __restrict__ XW) {
  alignas(16) __shared__ float xs[8][128];
  const int b = blockIdx.x >> 5, tg = blockIdx.x & 31, tid = threadIdx.x;
  const float* xg = x + ((size_t)b * LL + tg * 8) * 128;
  if (tid < 256) ((float4*)&xs[0][0])[tid] = ((const float4*)xg)[tid];
  __syncthreads();
  float acc[8];
#pragma unroll
  for (int r = 0; r < 8; r++) acc[r] = 0.f;
#pragma unroll 8
  for (int i4 = 0; i4 < 32; i4++) {
    float4 w4 = WrT4[i4 * 512 + tid];
#pragma unroll
    for (int r = 0; r < 8; r++) {
      float4 v = *(const float4*)&xs[r][4 * i4];
      acc[r] += w4.x * v.x + w4.y * v.y + w4.z * v.z + w4.w * v.w;
    }
  }
  const float brj = br[tid];
  float* o = XW + ((size_t)b * LL + tg * 8) * 512;
#pragma unroll
  for (int r = 0; r < 8; r++) o[r * 512 + tid] = acc[r] + brj;
}

// ---- Reader: sequential LSTM scan, Ur register-resident -------------------
__global__ __launch_bounds__(512, 2) void reader_kernel(const float4* __restrict__ UrT4,
                                                        const float* __restrict__ XW,
                                                        float* __restrict__ og) {
  alignas(16) __shared__ float h_s[128];
  alignas(16) __shared__ float pp_s[512];
  const int b = blockIdx.x, tid = threadIdx.x;
  const float* XWb = XW + (size_t)b * LL * 512;
  float* ogb = og + (size_t)b * LL * 128;

  float4 U[32];  // column tid of Ur, held for the whole scan (128 VGPRs)
#pragma unroll
  for (int i4 = 0; i4 < 32; i4++) U[i4] = UrT4[i4 * 512 + tid];

  float c_r = 0.f;
  if (tid < 128) h_s[tid] = 0.f;
  float xwv = XWb[tid];  // z-row for t=0 (x@Wr + br precomputed)
  __syncthreads();

  for (int t = 0; t < LL; t++) {
    float xw_n = (t + 1 < LL) ? XWb[(t + 1) * 512 + tid] : 0.f;  // prefetch
    v2f acc[4] = {{0.f, 0.f}, {0.f, 0.f}, {0.f, 0.f}, {0.f, 0.f}};
#pragma unroll
    for (int i4 = 0; i4 < 32; i4++) {  // full unroll: U[i4] must stay static
      float4 v = *(const float4*)&h_s[4 * i4];
      float4 w = U[i4];
      acc[i4 & 3] += (v2f){w.x, w.y} * (v2f){v.x, v.y};
      acc[i4 & 3] += (v2f){w.z, w.w} * (v2f){v.z, v.w};
    }
    v2f A = (acc[0] + acc[1]) + (acc[2] + acc[3]);
    pp_s[tid] = A.x + A.y + xwv;
    __syncthreads();
    if (tid < 128) {
      float zi = pp_s[tid], zf = pp_s[128 + tid], zg = pp_s[256 + tid], zo = pp_s[384 + tid];
      float ii = hsig(zi), ff = hsig(zf), gg = tanh_fast(zg), oo = hsig(zo);
      c_r = fmaf(ff, c_r, ii * gg);
      float h = oo * tanh_fast(c_r);
      h_s[tid] = h;
      ogb[t * 128 + tid] = h;
    }
    __syncthreads();
    xwv = xw_n;
  }
}

// ---- Writer: attention-memory scan ---------------------------------------
// z = ZW_t + m_rt@Vw + h@Uw. Vw tiles 0..15 in registers, 16..31 from L2;
// Uw tiles [0,NC) from LDS, [NC,32) from L2, computed at loop top (h=h_{t-1}).
template <int NC>
__global__ __launch_bounds__(512, 2) void writer_kernel(
    const float* __restrict__ x,
    const float4* __restrict__ VwT4, const float4* __restrict__ UwT4,
    const float* __restrict__ og, const float* __restrict__ ZW,
    float* __restrict__ out) {
  alignas(16) __shared__ float h_s[128];
  alignas(16) __shared__ float osN[128];   // o_{t+1} (o_0 during prologue)
  alignas(16) __shared__ float sc_s[256], ee_s[256];
  alignas(16) __shared__ float mr_s[128];
  alignas(16) __shared__ float pp_s[1024];
  __shared__ float rr_s[16];
  extern __shared__ float4 UwL[];          // NC*512 float4 Uw k-tile cache

  const int b = blockIdx.x, tid = threadIdx.x;
  const int lane = tid & 63, wv = tid >> 6;
  const int l = tid >> 1, hf = tid & 1;    // row-major role
  const int q = tid >> 6, dp = tid & 63;   // col-major role

  const float* xg = x + (size_t)b * (LL * 128);
  const float* ogb = og + (size_t)b * (LL * 128);
  const float* ZWb = ZW + (size_t)b * (LL * 512);

  // stage Uw k-tiles [0,NC) into LDS once (144KB at NC=18)
  for (int i = tid; i < NC * 512; i += 512) UwL[i] = UwT4[i];

  // Vw k-tiles 0..15, column tid, held in registers (64 VGPRs)
  float4 VR[16];
#pragma unroll
  for (int i4 = 0; i4 < 16; i4++) VR[i4] = VwT4[i4 * 512 + tid];

  // register-resident mem, two layouts (fp32 pairs) — 128 VGPRs persistent.
  v2f Mr[32], Mc[32];
#pragma unroll
  for (int w = 0; w < 32; w++) Mr[w] = *(const v2f*)(xg + l * 128 + hf * 64 + 2 * w);
#pragma unroll
  for (int i = 0; i < 32; i++) Mc[i] = *(const v2f*)(xg + (q * 32 + i) * 128 + 2 * dp);

  float c_w = 0.f;
  if (tid < 128) { h_s[tid] = 0.f; osN[tid] = ogb[tid]; }
  __syncthreads();
  { // prologue: sc_s[l] = mem0[l] . o_0
    v2f S = {0.f, 0.f};
#pragma unroll
    for (int w = 0; w < 32; w++) S += Mr[w] * (*(const v2f*)&osN[hf * 64 + 2 * w]);
    float s = S.x + S.y;
    s += __shfl_xor(s, 1);
    if (hf == 0) sc_s[l] = s;
  }
  __syncthreads();

  for (int t = 0; t < LL; t++) {
    // S0: huv = ZW_t[j] + h_{t-1}@Uw — legal at loop top (h_s stable since
    // prev step's gates; S5 is its only consumer). Overlaps softmax S1-S4.
    float huv;
    {
      float zwv = ZWb[(size_t)t * 512 + tid];
      v2f u0 = {0.f, 0.f}, u1 = {0.f, 0.f};
#pragma unroll 2
      for (int i4 = NC; i4 < 32; i4 += 2) {  // streamed Uw (L2)
        float4 w0 = UwT4[i4 * 512 + tid];
        float4 w1 = UwT4[(i4 + 1) * 512 + tid];
        float4 v0 = *(const float4*)&h_s[4 * i4];
        float4 v1 = *(const float4*)&h_s[4 * i4 + 4];
        u0 += (v2f){w0.x, w0.y} * (v2f){v0.x, v0.y};
        u0 += (v2f){w0.z, w0.w} * (v2f){v0.z, v0.w};
        u1 += (v2f){w1.x, w1.y} * (v2f){v1.x, v1.y};
        u1 += (v2f){w1.z, w1.w} * (v2f){v1.z, v1.w};
      }
#pragma unroll 2
      for (int i4 = 0; i4 < NC; i4 += 2) {  // cached Uw (LDS)
        float4 w0 = UwL[i4 * 512 + tid];
        float4 w1 = UwL[(i4 + 1) * 512 + tid];
        float4 v0 = *(const float4*)&h_s[4 * i4];
        float4 v1 = *(const float4*)&h_s[4 * i4 + 4];
        u0 += (v2f){w0.x, w0.y} * (v2f){v0.x, v0.y};
        u0 += (v2f){w0.z, w0.w} * (v2f){v0.z, v0.w};
        u1 += (v2f){w1.x, w1.y} * (v2f){v1.x, v1.y};
        u1 += (v2f){w1.z, w1.w} * (v2f){v1.z, v1.w};
      }
      v2f U = u0 + u1;
      huv = U.x + U.y + zwv;
    }
    // S1: load o_{t+1}; softmax max
    if (tid >= 128 && tid < 256 && t + 1 < LL)
      osN[tid - 128] = ogb[(t + 1) * 128 + (tid - 128)];
    if (tid < 256) {
      float m = sc_s[tid];
#pragma unroll
      for (int off = 32; off > 0; off >>= 1) m = fmaxf(m, __shfl_xor(m, off));
      if (lane == 0) rr_s[wv] = m;
    }
    __syncthreads();
    // S2: exp + sum
    if (tid < 256) {
      float mx = fmaxf(fmaxf(rr_s[0], rr_s[1]), fmaxf(rr_s[2], rr_s[3]));
      float e = __expf(sc_s[tid] - mx);
      ee_s[tid] = e;
      float s2 = e;
#pragma unroll
      for (int off = 32; off > 0; off >>= 1) s2 += __shfl_xor(s2, off);
      if (lane == 0) rr_s[8 + wv] = s2;
    }
    __syncthreads();
    const float inv = 1.f / (rr_s[8] + rr_s[9] + rr_s[10] + rr_s[11]);
    // S3: m_rt partials (col-major, register-local)
    {
      v2f P = {0.f, 0.f};
#pragma unroll
      for (int i = 0; i < 32; i++) P += Mc[i] * ee_s[q * 32 + i];
      *(v2f*)&pp_s[q * 128 + 2 * dp] = P;
    }
    __syncthreads();
    // S4: m_rt final
    if (tid < 128) {
      float s = 0.f;
#pragma unroll
      for (int g = 0; g < 8; g++) s += pp_s[g * 128 + tid];
      mr_s[tid] = s * inv;
    }
    __syncthreads();
    // S5: z[j] = huv + m_rt@Vw — tiles 0..15 from registers, 16..31 from L2.
    {
      v2f a0 = {0.f, 0.f}, a1 = {0.f, 0.f}, a2 = {0.f, 0.f}, a3 = {0.f, 0.f};
#pragma unroll 2
      for (int i4 = 16; i4 < 32; i4 += 2) {  // streamed Vw (L2)
        float4 w0 = VwT4[i4 * 512 + tid];
        float4 w1 = VwT4[(i4 + 1) * 512 + tid];
        float4 v0 = *(const float4*)&mr_s[4 * i4];
        float4 v1 = *(const float4*)&mr_s[4 * i4 + 4];
        a0 += (v2f){w0.x, w0.y} * (v2f){v0.x, v0.y};
        a0 += (v2f){w0.z, w0.w} * (v2f){v0.z, v0.w};
        a1 += (v2f){w1.x, w1.y} * (v2f){v1.x, v1.y};
        a1 += (v2f){w1.z, w1.w} * (v2f){v1.z, v1.w};
      }
#pragma unroll
      for (int i4 = 0; i4 < 16; i4 += 2) {  // register-held Vw
        float4 w0 = VR[i4];
        float4 w1 = VR[i4 + 1];
        float4 v0 = *(const float4*)&mr_s[4 * i4];
        float4 v1 = *(const float4*)&mr_s[4 * i4 + 4];
        a2 += (v2f){w0.x, w0.y} * (v2f){v0.x, v0.y};
        a2 += (v2f){w0.z, w0.w} * (v2f){v0.z, v0.w};
        a3 += (v2f){w1.x, w1.y} * (v2f){v1.x, v1.y};
        a3 += (v2f){w1.z, w1.w} * (v2f){v1.z, v1.w};
      }
      v2f A = (a0 + a2) + (a1 + a3);
      pp_s[tid] = A.x + A.y + huv;
    }
    __syncthreads();
    // S6: gates
    if (tid < 128) {
      float zi = pp_s[tid], zf = pp_s[128 + tid], zg = pp_s[256 + tid], zo = pp_s[384 + tid];
      float ii = hsig(zi), ff = hsig(zf), gg = tanh_fast(zg), oo = hsig(zo);
      c_w = fmaf(ff, c_w, ii * gg);
      h_s[tid] = oo * tanh_fast(c_w);
    }
    __syncthreads();
    // S7: mem update (both layouts, identical math) + fused next scores
    if (t + 1 < LL) {
      const float zr = ee_s[l] * inv;
      v2f S = {0.f, 0.f};
#pragma unroll
      for (int w = 0; w < 32; w++) {
        v2f h2 = *(const v2f*)&h_s[hf * 64 + 2 * w];
        v2f m = Mr[w];
        v2f n = m + (h2 - m) * zr;
        Mr[w] = n;
        S += n * (*(const v2f*)&osN[hf * 64 + 2 * w]);
      }
      float s = S.x + S.y;
      s += __shfl_xor(s, 1);
      if (hf == 0) sc_s[l] = s;
      v2f hc = *(const v2f*)&h_s[2 * dp];
#pragma unroll
      for (int i = 0; i < 32; i++) {
        float zc = ee_s[q * 32 + i] * inv;
        v2f m = Mc[i];
        Mc[i] = m + (hc - m) * zc;
      }
    }
    __syncthreads();
  }

  if (tid < 128) out[b * 128 + tid] = h_s[tid];
}

extern "C" void kernel_launch(void* const* d_in, const int* in_sizes, int n_in,
                              void* d_out, int out_size, void* d_ws, size_t ws_size,
                              hipStream_t stream) {
  const float* x  = (const float*)d_in[0];
  const float* Wr = (const float*)d_in[1];
  const float* Ur = (const float*)d_in[2];
  const float* br = (const float*)d_in[3];
  const float* Ww = (const float*)d_in[4];
  const float* Uw = (const float*)d_in[5];
  const float* bw = (const float*)d_in[6];
  const float* Wc = (const float*)d_in[7];
  const float* bc = (const float*)d_in[8];
  float* out = (float*)d_out;

  // workspace (floats): og 1,048,576 | XW/ZW 4,194,304 | WrT 65,536 |
  // UrT 65,536 | UwT 65,536 | PVw 131,072 | PwT 65,536 | VwT 65,536 | pz 512
  // total 5,702,656 floats = 22.8 MB
  float* og  = (float*)d_ws;
  float* XW  = og + 1048576;   // ZW aliases XW (XW dead after reader)
  float* WrT = XW + 4194304;
  float* UrT = WrT + 65536;
  float* UwT = UrT + 65536;
  float* PVw = UwT + 65536;
  float* PwT = PVw + 131072;
  float* VwT = PwT + 65536;
  float* pz  = VwT + 65536;

  // big-LDS opt-in for the Uw cache (capture-safe: not a stream op).
  static int nc_cached = -1;
  if (nc_cached < 0) {
    int want = 18 * 512 * (int)sizeof(float4);  // 147456 B dynamic
    nc_cached = (hipFuncSetAttribute(
                     reinterpret_cast<const void*>(&writer_kernel<18>),
                     hipFuncAttributeMaxDynamicSharedMemorySize, want) == hipSuccess)
                    ? 18
                    : 6;  // fallback: 48KB dynamic, under default 64KB limit
  }

  wtrans_kernel<<<128, 512, 0, stream>>>(Wr, WrT, 9);
  wtrans_kernel<<<128, 512, 0, stream>>>(Ur, UrT, 9);
  wtrans_kernel<<<128, 512, 0, stream>>>(Uw, UwT, 9);
  pvw_gemm<<<256, 512, 0, stream>>>(Wc, Ww, PVw);
  pz_kernel<<<1, 512, 0, stream>>>(bc, Ww, bw, pz);
  wtrans_kernel<<<128, 512, 0, stream>>>(PVw, PwT, 9);
  wtrans_kernel<<<128, 512, 0, stream>>>(PVw + 65536, VwT, 9);
  xw_gemm<<<1024, 512, 0, stream>>>(x, (const float4*)WrT, br, XW);
  reader_kernel<<<32, 512, 0, stream>>>((const float4*)UrT, XW, og);
  xw_gemm<<<1024, 512, 0, stream>>>(og, (const float4*)PwT, pz, XW);  // ZW
  if (nc_cached == 18) {
    writer_kernel<18><<<32, 512, 18 * 512 * sizeof(float4), stream>>>(
        x, (const float4*)VwT, (const float4*)UwT, og, XW, out);
  } else {
    writer_kernel<6><<<32, 512, 6 * 512 * sizeof(float4), stream>>>(
        x, (const float4*)VwT, (const float4*)UwT, og, XW, out);
  }
}